// Round 1
// baseline (316.369 us; speedup 1.0000x reference)
//
#include <hip/hip_runtime.h>

// LateralInhibition: out = inputs * ((inputs @ w1 + b) > 0), w1 = w with zero diag.
// inputs: [M=32768, 512] fp32 row-major; w: [512,512] fp32 row-major (w[k][n]).
// fp32 vector-ALU SGEMM (no fp32 MFMA on CDNA4), BM=BN=128 BK=16, 8x8/thread.

#define NUMD 512
#define BM 128
#define BN 128
#define BK 16
#define TM 8
#define TN 8
#define PAD 4   // LDS row pad: keeps 16B alignment, makes staging write conflicts 2-way (free)

__global__ __launch_bounds__(256) void li_gemm_gate(
    const float* __restrict__ A,    // [M, 512]
    const float* __restrict__ W,    // [512, 512]
    const float* __restrict__ bias, // [512]
    float* __restrict__ out,        // [M, 512]
    int M)
{
    __shared__ __align__(16) float As[BK][BM + PAD]; // transposed: As[k][m]
    __shared__ __align__(16) float Bs[BK][BN + PAD]; // Bs[k][n]

    const int tid = threadIdx.x;
    const int tc  = tid & 15;   // column group (n), fast -> coalesced C writes
    const int tr  = tid >> 4;   // row group (m)
    const int m0  = blockIdx.x * BM;
    const int n0  = blockIdx.y * BN;

    // --- staging index maps ---
    // A: thread loads 8 consecutive k-floats of one row
    const int arow = tid >> 1;         // 0..127
    const int acol = (tid & 1) * 8;    // 0 or 8
    // B: thread loads float4 of rows brow and brow+8
    const int brow = tid >> 5;         // 0..7
    const int bcol = (tid & 31) * 4;   // 0..124

    const float* Aptr = A + (size_t)(m0 + arow) * NUMD + acol;
    const float* Wptr = W + (size_t)brow * NUMD + n0 + bcol;

    float acc[TM][TN];
#pragma unroll
    for (int i = 0; i < TM; ++i)
#pragma unroll
        for (int j = 0; j < TN; ++j) acc[i][j] = 0.0f;

    // prefetch tile 0
    float4 ar0 = *(const float4*)(Aptr);
    float4 ar1 = *(const float4*)(Aptr + 4);
    float4 br0 = *(const float4*)(Wptr);
    float4 br1 = *(const float4*)(Wptr + 8 * NUMD);

    const int NT = NUMD / BK; // 32
    for (int kt = 0; kt < NT; ++kt) {
        const int kk = kt * BK;

        // zero the diagonal of w during staging: Bs[k][j] = w[kk+k][n0+j], diag when kk+k == n0+j
        {
            int d0 = (kk + brow) - (n0 + bcol);
            if (d0 >= 0 && d0 < 4) ((float*)&br0)[d0] = 0.0f;
            int d1 = (kk + brow + 8) - (n0 + bcol);
            if (d1 >= 0 && d1 < 4) ((float*)&br1)[d1] = 0.0f;
        }

        // store staged regs to LDS (A transposed)
#pragma unroll
        for (int j = 0; j < 4; ++j) {
            As[acol + j][arow]     = ((const float*)&ar0)[j];
            As[acol + 4 + j][arow] = ((const float*)&ar1)[j];
        }
        *(float4*)&Bs[brow][bcol]     = br0;
        *(float4*)&Bs[brow + 8][bcol] = br1;
        __syncthreads();

        // prefetch next tile while computing this one
        if (kt + 1 < NT) {
            Aptr += BK;
            Wptr += BK * NUMD;
            ar0 = *(const float4*)(Aptr);
            ar1 = *(const float4*)(Aptr + 4);
            br0 = *(const float4*)(Wptr);
            br1 = *(const float4*)(Wptr + 8 * NUMD);
        }

        // inner product over this K-slab
#pragma unroll
        for (int k = 0; k < BK; ++k) {
            const float* ap = &As[k][tr * TM];
            const float* bp = &Bs[k][tc * TN];
            float4 a0 = *(const float4*)ap;
            float4 a1 = *(const float4*)(ap + 4);
            float4 b0 = *(const float4*)bp;
            float4 b1 = *(const float4*)(bp + 4);
            float a[TM] = {a0.x, a0.y, a0.z, a0.w, a1.x, a1.y, a1.z, a1.w};
            float b[TN] = {b0.x, b0.y, b0.z, b0.w, b1.x, b1.y, b1.z, b1.w};
#pragma unroll
            for (int i = 0; i < TM; ++i)
#pragma unroll
                for (int j = 0; j < TN; ++j)
                    acc[i][j] = fmaf(a[i], b[j], acc[i][j]);
        }
        __syncthreads();
    }

    // epilogue: out[m][n] = in[m][n] * ((acc + b[n]) > 0)
    float bv[TN];
#pragma unroll
    for (int j = 0; j < TN; ++j) bv[j] = bias[n0 + tc * TN + j];

#pragma unroll
    for (int i = 0; i < TM; ++i) {
        const int gm = m0 + tr * TM + i;
        const float* inrow = A + (size_t)gm * NUMD + n0 + tc * TN;
        float4 x0 = *(const float4*)inrow;
        float4 x1 = *(const float4*)(inrow + 4);
        float x[TN] = {x0.x, x0.y, x0.z, x0.w, x1.x, x1.y, x1.z, x1.w};
        float o[TN];
#pragma unroll
        for (int j = 0; j < TN; ++j) {
            float inh = acc[i][j] + bv[j];
            o[j] = (inh > 0.0f) ? x[j] : 0.0f;
        }
        float4 o0 = {o[0], o[1], o[2], o[3]};
        float4 o1 = {o[4], o[5], o[6], o[7]};
        float* orow = out + (size_t)gm * NUMD + n0 + tc * TN;
        *(float4*)orow       = o0;
        *(float4*)(orow + 4) = o1;
    }
}

extern "C" void kernel_launch(void* const* d_in, const int* in_sizes, int n_in,
                              void* d_out, int out_size, void* d_ws, size_t ws_size,
                              hipStream_t stream) {
    const float* A    = (const float*)d_in[0]; // inputs [8*4096, 512]
    const float* W    = (const float*)d_in[1]; // w [512, 512]
    const float* bias = (const float*)d_in[2]; // b [512]
    float* out        = (float*)d_out;

    const int M = in_sizes[0] / NUMD; // 32768
    dim3 grid(M / BM, NUMD / BN);     // (256, 4)
    li_gemm_gate<<<grid, 256, 0, stream>>>(A, W, bias, out, M);
}